// Round 4
// baseline (310.106 us; speedup 1.0000x reference)
//
#include <hip/hip_runtime.h>
#include <math.h>

#define TT 4
#define CC 3
#define HH 192
#define WW 192
#define SS 300          // n_spix
#define SP 320          // padded (pad entries masked absent)
#define KS 7
#define PD 3
#define TS 16           // output tile
#define HSZ 22          // tile + 2*PD halo
#define NHP (HSZ*HSZ)   // 484
#define SC 32           // superpixel chunk (64 B of fp16 per row)
#define HW (HH*WW)
#define PSTR (HW + 16)  // sims plane stride in 16B units (16 guard slots, zeroed)
#define NPLANE (TT*40)  // 40 s8-planes per frame
#define SIMS_OFF 16384  // float offset of sims table in ws
#define NSLOT 1984      // 496 rows x 4 slots staged per chunk (484 used)

typedef _Float16 h2 __attribute__((ext_vector_type(2)));
typedef _Float16 h8 __attribute__((ext_vector_type(8)));

// ---------- ws layout (floats) ----------
// [0, 3600)      sums [T][S][3]
// [3600, 4800)   cnts [T][S]
// [4800, 9920)   means float4 [T][SP] (xyz mean, w = 0 present / -inf absent)
// [16384, ...)   sims fp16 table: [t*40+s8][PSTR][8 halves]; guard px [HW,HW+16) zeroed

__global__ void k_zero(float* ws) {
    int i = blockIdx.x * 256 + threadIdx.x;
    if (i < TT * SS * 4) { ws[i] = 0.f; return; }
    int j = i - TT * SS * 4;                 // guard-slot zeroing: 160 planes x 64 floats
    if (j < NPLANE * 64) {
        int q = j >> 6, r = j & 63;
        ws[SIMS_OFF + ((long)q * PSTR + HW) * 4 + r] = 0.f;
    }
}

__global__ void k_accum(const float* __restrict__ x, const int* __restrict__ spix,
                        float* __restrict__ ws) {
    int i = blockIdx.x * 256 + threadIdx.x;
    if (i >= TT * HW) return;
    int t = i / HW, p = i - t * HW;
    int s = spix[i];
    float* sums = ws;
    float* cnts = ws + TT * SS * 3;
    int b = (t * SS + s) * 3;
    atomicAdd(&sums[b + 0], x[(t * 3 + 0) * HW + p]);
    atomicAdd(&sums[b + 1], x[(t * 3 + 1) * HW + p]);
    atomicAdd(&sums[b + 2], x[(t * 3 + 2) * HW + p]);
    atomicAdd(&cnts[t * SS + s], 1.f);
}

__global__ void k_means(float* __restrict__ ws) {
    int i = blockIdx.x * 256 + threadIdx.x;
    if (i >= TT * SP) return;
    int t = i / SP, s = i - t * SP;
    const float* sums = ws;
    const float* cnts = ws + TT * SS * 3;
    float4* m4 = (float4*)(ws + TT * SS * 3 + TT * SS);
    float4 m;
    if (s < SS) {
        float c = cnts[t * SS + s];
        float inv = 1.f / fmaxf(c, 1.f);
        m.x = sums[(t * SS + s) * 3 + 0] * inv;
        m.y = sums[(t * SS + s) * 3 + 1] * inv;
        m.z = sums[(t * SS + s) * 3 + 2] * inv;
        m.w = (c > 0.f) ? 0.f : -INFINITY;
    } else {
        m.x = 0.f; m.y = 0.f; m.z = 0.f; m.w = -INFINITY;
    }
    m4[t * SP + s] = m;
}

// ---- per-pixel normalized fp16 sims -> global table (3-pass softmax) ----
__launch_bounds__(128)
__global__ void k_sims(const float* __restrict__ x, float* __restrict__ ws) {
    __shared__ float4 smean[SP];
    const int tid = threadIdx.x;
    const int t = blockIdx.y;
    const int p0 = blockIdx.x * 256 + tid;      // 2 px/thread: p0, p0+128
    const int p1 = p0 + 128;

    const float4* m4 = (const float4*)(ws + TT * SS * 3 + TT * SS) + t * SP;
    for (int i = tid; i < SP; i += 128) smean[i] = m4[i];
    __syncthreads();

    float f0x = x[(t * 3 + 0) * HW + p0], f0y = x[(t * 3 + 1) * HW + p0], f0z = x[(t * 3 + 2) * HW + p0];
    float f1x = x[(t * 3 + 0) * HW + p1], f1y = x[(t * 3 + 1) * HW + p1], f1z = x[(t * 3 + 2) * HW + p1];

    float mn0 = INFINITY, mn1 = INFINITY;
#pragma unroll 4
    for (int s = 0; s < SP; s++) {
        float4 m = smean[s];
        float a0 = f0x - m.x, b0 = f0y - m.y, c0 = f0z - m.z;
        float a1 = f1x - m.x, b1 = f1y - m.y, c1 = f1z - m.z;
        mn0 = fminf(mn0, a0 * a0 + b0 * b0 + c0 * c0 - m.w);   // absent: +inf
        mn1 = fminf(mn1, a1 * a1 + b1 * b1 + c1 * c1 - m.w);
    }
    float tm0 = 10.f * mn0, tm1 = 10.f * mn1;
    float Z0 = 0.f, Z1 = 0.f;
#pragma unroll 4
    for (int s = 0; s < SP; s++) {
        float4 m = smean[s];
        float a0 = f0x - m.x, b0 = f0y - m.y, c0 = f0z - m.z;
        float a1 = f1x - m.x, b1 = f1y - m.y, c1 = f1z - m.z;
        Z0 += __expf(fmaf(-10.f, a0 * a0 + b0 * b0 + c0 * c0, tm0) + m.w);  // absent: 0
        Z1 += __expf(fmaf(-10.f, a1 * a1 + b1 * b1 + c1 * c1, tm1) + m.w);
    }
    float iZ0 = 1.f / Z0, iZ1 = 1.f / Z1;

    _Float16* sims = (_Float16*)(ws + SIMS_OFF);
#pragma unroll 1
    for (int s8 = 0; s8 < 40; s8++) {
        h8 v0, v1;
#pragma unroll
        for (int j = 0; j < 8; j++) {
            float4 m = smean[s8 * 8 + j];
            float a0 = f0x - m.x, b0 = f0y - m.y, c0 = f0z - m.z;
            float a1 = f1x - m.x, b1 = f1y - m.y, c1 = f1z - m.z;
            v0[j] = (_Float16)(__expf(fmaf(-10.f, a0 * a0 + b0 * b0 + c0 * c0, tm0) + m.w) * iZ0);
            v1[j] = (_Float16)(__expf(fmaf(-10.f, a1 * a1 + b1 * b1 + c1 * c1, tm1) + m.w) * iZ1);
        }
        long pl = (long)(t * 40 + s8) * PSTR;
        *(h8*)&sims[(pl + p0) * 8] = v0;
        *(h8*)&sims[(pl + p1) * 8] = v1;
    }
}

#define REP49(M) M(0)M(1)M(2)M(3)M(4)M(5)M(6)M(7)M(8)M(9)M(10)M(11)M(12)M(13) \
    M(14)M(15)M(16)M(17)M(18)M(19)M(20)M(21)M(22)M(23)M(24)M(25)M(26)M(27) \
    M(28)M(29)M(30)M(31)M(32)M(33)M(34)M(35)M(36)M(37)M(38)M(39)M(40)M(41) \
    M(42)M(43)M(44)M(45)M(46)M(47)M(48)

#define QOFF(k) (((k) / 7 - PD) * HSZ + ((k) % 7 - PD))
#define SWZ(q) (((q) ^ ((q) >> 2)) & 3)

#define D2(a, A, B, i) a = __builtin_amdgcn_fdot2( \
        __builtin_shufflevector(A, A, 2*(i), 2*(i)+1), \
        __builtin_shufflevector(B, B, 2*(i), 2*(i)+1), a, false);

__device__ __forceinline__ void gload_lds16(const void* g, void* l) {
    __builtin_amdgcn_global_load_lds(g, l, 16, 0, 0);
}

__launch_bounds__(256, 3)
__global__ void k_main(const float* __restrict__ x, const float* __restrict__ Wlin,
                       const float* __restrict__ blin, const float* __restrict__ ws,
                       float* __restrict__ out) {
    __shared__ float4 sfh[NHP];                        // x features for epilogue
    __shared__ float  sW[CC * CC * KS * KS];           // 441
    __shared__ __align__(16) _Float16 ssim[496 * 32];  // 31.75 KB, linear 64B rows

    const int tid = threadIdx.x;
    const int tx = tid & 15, ty = tid >> 4;
    const int w = tid >> 6, lane = tid & 63;
    const int t = blockIdx.z;
    const int gx0 = blockIdx.x * TS - PD, gy0 = blockIdx.y * TS - PD;

    for (int i = tid; i < CC * CC * KS * KS; i += 256) sW[i] = Wlin[i];

    // ---- stage x features for the epilogue ----
    for (int hp = tid; hp < NHP; hp += 256) {
        int hy = hp / HSZ, hx = hp - hy * HSZ;
        int gy = gy0 + hy, gx = gx0 + hx;
        bool inb = (gy >= 0 && gy < HH && gx >= 0 && gx < WW);
        float fx = 0.f, fy = 0.f, fz = 0.f;
        if (inb) {
            int p = gy * WW + gx;
            fx = x[(t * 3 + 0) * HW + p];
            fy = x[(t * 3 + 1) * HW + p];
            fz = x[(t * 3 + 2) * HW + p];
        }
        sfh[hp] = make_float4(fx, fy, fz, 0.f);
    }

    // ---- precompute per-lane staging source pointers (chunk 0) ----
    // slot g = i*64 + lane holds (hp = g>>2, jb_slot = g&3) -> data block jd = jb_slot ^ SWZ(hp)
    const char* simsb = (const char*)(ws + SIMS_OFF);
    const char* src[8];
#pragma unroll
    for (int j = 0; j < 8; j++) {
        int i = w + 4 * j;
        int g = i * 64 + lane;
        int hp = g >> 2, jbs = g & 3;
        int jd = jbs ^ SWZ(hp);
        int hy = hp / HSZ, hx = hp - hy * HSZ;
        int gy = gy0 + hy, gx = gx0 + hx;
        bool ok = (hp < NHP) && (gy >= 0) && (gy < HH) && (gx >= 0) && (gx < WW);
        long p = ok ? (long)(gy * WW + gx) : (long)(HW + (g & 15));   // guard: zeros
        src[j] = simsb + (((long)(t * 40 + jd) * PSTR + p) << 4);
    }
    const long chunk_step = ((long)4 * PSTR) << 4;   // next 4 s8-planes

#define ZK(k) float acc##k = 0.f;
    REP49(ZK)
#undef ZK
    const int own = (ty + PD) * HSZ + (tx + PD);
    const int osz = SWZ(own);
    const h8* orow = (const h8*)&ssim[own << 5];

#pragma unroll 1
    for (int c = 0; c < 10; c++) {
        // ---- stage chunk c: 31 x global_load_lds dwordx4 (linear LDS dest) ----
#pragma unroll
        for (int j = 0; j < 8; j++) {
            if (w + 4 * j < 31)
                gload_lds16((const void*)src[j], (void*)&ssim[(w + 4 * j) * 512]);
            src[j] += chunk_step;
        }
        __syncthreads();   // drains vmcnt: chunk staged (also covers sfh/sW on c==0)
        // ---- own row (data blocks in order) ----
        h8 ow0 = orow[0 ^ osz], ow1 = orow[1 ^ osz], ow2 = orow[2 ^ osz], ow3 = orow[3 ^ osz];
        // ---- 49 offsets x 4 ds_read_b128 x 16 v_dot2_f32_f16 ----
#define MACK(k) { \
        const int q = own + QOFF(k); \
        const int sz = SWZ(q); \
        const h8* nr = (const h8*)&ssim[q << 5]; \
        h8 q0 = nr[0 ^ sz], q1 = nr[1 ^ sz], q2 = nr[2 ^ sz], q3 = nr[3 ^ sz]; \
        float aA = acc##k, aB = 0.f; \
        D2(aA, ow0, q0, 0) D2(aB, ow0, q0, 1) D2(aA, ow0, q0, 2) D2(aB, ow0, q0, 3) \
        D2(aA, ow1, q1, 0) D2(aB, ow1, q1, 1) D2(aA, ow1, q1, 2) D2(aB, ow1, q1, 3) \
        D2(aA, ow2, q2, 0) D2(aB, ow2, q2, 1) D2(aA, ow2, q2, 2) D2(aB, ow2, q2, 3) \
        D2(aA, ow3, q3, 0) D2(aB, ow3, q3, 1) D2(aA, ow3, q3, 2) D2(aB, ow3, q3, 3) \
        acc##k = aA + aB; }
        REP49(MACK)
#undef MACK
        __syncthreads();   // MAC reads done before next chunk overwrites
    }

    // ---- max-normalize + linear epilogue ----
    float mx = 0.f;
#define MXK(k) mx = fmaxf(mx, acc##k);
    REP49(MXK)
#undef MXK
    float inv = 1.f / (1e-5f + mx);

    float o0 = blin[0], o1 = blin[1], o2 = blin[2];
#define EPIK(k) { \
        float rwk = acc##k * inv; \
        float4 f = sfh[own + QOFF(k)]; \
        o0 += rwk * (sW[0 * 147 + (k)] * f.x + sW[0 * 147 + 49 + (k)] * f.y + sW[0 * 147 + 98 + (k)] * f.z); \
        o1 += rwk * (sW[1 * 147 + (k)] * f.x + sW[1 * 147 + 49 + (k)] * f.y + sW[1 * 147 + 98 + (k)] * f.z); \
        o2 += rwk * (sW[2 * 147 + (k)] * f.x + sW[2 * 147 + 49 + (k)] * f.y + sW[2 * 147 + 98 + (k)] * f.z); }
    REP49(EPIK)
#undef EPIK

    int gy = gy0 + PD + ty, gx = gx0 + PD + tx;
    int p = gy * WW + gx;
    out[(t * 3 + 0) * HW + p] = o0;
    out[(t * 3 + 1) * HW + p] = o1;
    out[(t * 3 + 2) * HW + p] = o2;
}

// ================= fallback (round-3 kernel) if ws too small =================
#define SROW 40
__launch_bounds__(256, 3)
__global__ void k_main_fb(const float* __restrict__ x, const float* __restrict__ Wlin,
                          const float* __restrict__ blin, const float* __restrict__ ws,
                          float* __restrict__ out) {
    __shared__ float4 sfh[NHP];
    __shared__ float  sW[CC * CC * KS * KS];
    __shared__ __align__(16) _Float16 ssim[NHP * SROW];

    const int tid = threadIdx.x;
    const int tx = tid & 15, ty = tid >> 4;
    const int t = blockIdx.z;
    const int gx0 = blockIdx.x * TS - PD, gy0 = blockIdx.y * TS - PD;
    const float4* m4 = (const float4*)(ws + TT * SS * 3 + TT * SS) + t * SP;

    for (int i = tid; i < CC * CC * KS * KS; i += 256) sW[i] = Wlin[i];

    for (int hp = tid; hp < NHP; hp += 256) {
        int hy = hp / HSZ, hx = hp - hy * HSZ;
        int gy = gy0 + hy, gx = gx0 + hx;
        bool inb = (gy >= 0 && gy < HH && gx >= 0 && gx < WW);
        float fx = 0.f, fy = 0.f, fz = 0.f, cp = -INFINITY;
        if (inb) {
            int p = gy * WW + gx;
            fx = x[(t * 3 + 0) * HW + p];
            fy = x[(t * 3 + 1) * HW + p];
            fz = x[(t * 3 + 2) * HW + p];
            float d2min = INFINITY;
#pragma unroll 4
            for (int s = 0; s < SP; s++) {
                float4 m = m4[s];
                float a = fx - m.x, b = fy - m.y, c = fz - m.z;
                d2min = fminf(d2min, a * a + b * b + c * c - m.w);
            }
            float Z = 0.f;
#pragma unroll 4
            for (int s = 0; s < SP; s++) {
                float4 m = m4[s];
                float a = fx - m.x, b = fy - m.y, c = fz - m.z;
                Z += __expf(fmaf(-10.f, a * a + b * b + c * c, 10.f * d2min) + m.w);
            }
            cp = fmaf(10.f, d2min, -__logf(Z));
        }
        sfh[hp] = make_float4(fx, fy, fz, cp);
    }

#define ZK(k) float acc##k = 0.f;
    REP49(ZK)
#undef ZK
    const int own = (ty + PD) * HSZ + (tx + PD);

#pragma unroll 1
    for (int cs = 0; cs < SP; cs += SC) {
        __syncthreads();
        for (int hp = tid; hp < NHP; hp += 256) {
            float4 f = sfh[hp];
            h8* row = (h8*)&ssim[hp * SROW];
#pragma unroll
            for (int jb = 0; jb < 4; jb++) {
                h8 v;
#pragma unroll
                for (int j = 0; j < 8; j++) {
                    float4 m = m4[cs + jb * 8 + j];
                    float a = f.x - m.x, b = f.y - m.y, c = f.z - m.z;
                    v[j] = (_Float16)__expf(fmaf(-10.f, a * a + b * b + c * c, f.w) + m.w);
                }
                row[jb] = v;
            }
        }
        __syncthreads();
        const h8* orow = (const h8*)&ssim[(unsigned)own * SROW];
        h8 ow0 = orow[0], ow1 = orow[1], ow2 = orow[2], ow3 = orow[3];
#define MACK(k) { \
        const h8* nr = (const h8*)&ssim[(unsigned)(own + QOFF(k)) * SROW]; \
        h8 q0 = nr[0], q1 = nr[1], q2 = nr[2], q3 = nr[3]; \
        float aA = acc##k, aB = 0.f; \
        D2(aA, ow0, q0, 0) D2(aB, ow0, q0, 1) D2(aA, ow0, q0, 2) D2(aB, ow0, q0, 3) \
        D2(aA, ow1, q1, 0) D2(aB, ow1, q1, 1) D2(aA, ow1, q1, 2) D2(aB, ow1, q1, 3) \
        D2(aA, ow2, q2, 0) D2(aB, ow2, q2, 1) D2(aA, ow2, q2, 2) D2(aB, ow2, q2, 3) \
        D2(aA, ow3, q3, 0) D2(aB, ow3, q3, 1) D2(aA, ow3, q3, 2) D2(aB, ow3, q3, 3) \
        acc##k = aA + aB; }
        REP49(MACK)
#undef MACK
    }

    float mx = 0.f;
#define MXK(k) mx = fmaxf(mx, acc##k);
    REP49(MXK)
#undef MXK
    float inv = 1.f / (1e-5f + mx);
    float o0 = blin[0], o1 = blin[1], o2 = blin[2];
#define EPIK(k) { \
        float rwk = acc##k * inv; \
        float4 f = sfh[own + QOFF(k)]; \
        o0 += rwk * (sW[0 * 147 + (k)] * f.x + sW[0 * 147 + 49 + (k)] * f.y + sW[0 * 147 + 98 + (k)] * f.z); \
        o1 += rwk * (sW[1 * 147 + (k)] * f.x + sW[1 * 147 + 49 + (k)] * f.y + sW[1 * 147 + 98 + (k)] * f.z); \
        o2 += rwk * (sW[2 * 147 + (k)] * f.x + sW[2 * 147 + 49 + (k)] * f.y + sW[2 * 147 + 98 + (k)] * f.z); }
    REP49(EPIK)
#undef EPIK
    int gy = gy0 + PD + ty, gx = gx0 + PD + tx;
    int p = gy * WW + gx;
    out[(t * 3 + 0) * HW + p] = o0;
    out[(t * 3 + 1) * HW + p] = o1;
    out[(t * 3 + 2) * HW + p] = o2;
}

extern "C" void kernel_launch(void* const* d_in, const int* in_sizes, int n_in,
                              void* d_out, int out_size, void* d_ws, size_t ws_size,
                              hipStream_t stream) {
    const float* x    = (const float*)d_in[0];
    const int*   spix = (const int*)d_in[1];
    const float* Wlin = (const float*)d_in[2];
    const float* blin = (const float*)d_in[3];
    float* out = (float*)d_out;
    float* ws  = (float*)d_ws;

    const size_t NEED = (size_t)SIMS_OFF * 4 + (size_t)NPLANE * PSTR * 16;

    hipLaunchKernelGGL(k_zero,  dim3((TT * SS * 4 + NPLANE * 64 + 255) / 256), dim3(256), 0, stream, ws);
    hipLaunchKernelGGL(k_accum, dim3((TT * HW + 255) / 256), dim3(256), 0, stream, x, spix, ws);
    hipLaunchKernelGGL(k_means, dim3((TT * SP + 255) / 256), dim3(256), 0, stream, ws);
    if (ws_size >= NEED) {
        hipLaunchKernelGGL(k_sims, dim3(HW / 256, TT), dim3(128), 0, stream, x, ws);
        hipLaunchKernelGGL(k_main, dim3(WW / TS, HH / TS, TT), dim3(256), 0, stream,
                           x, Wlin, blin, ws, out);
    } else {
        hipLaunchKernelGGL(k_main_fb, dim3(WW / TS, HH / TS, TT), dim3(256), 0, stream,
                           x, Wlin, blin, ws, out);
    }
}